// Round 8
// baseline (271.620 us; speedup 1.0000x reference)
//
#include <hip/hip_runtime.h>
#include <math.h>

#define NPTS   4096   // points per set (n == m)
#define NPROJ  2000   // projections
#define NB     256    // threads per block (4 waves)
#define NMERGE 8192   // n + m
#define VPT    32     // values per thread (in registers)
#define HBINS  2048   // histogram over c in [-1024, 1023]; actual range ~±130
#define HOFF   1024

// XOR-rotate swizzle: element-within-chunk rotated by chunk index (chunk = i>>5).
__device__ __forceinline__ int sw(int i) {
    return (i & ~31) | ((i + (i >> 5)) & 31);
}

// Bitonic local merge of 32 in-register elements, steps j=16..1, uniform direction.
__device__ __forceinline__ void local_merge(float v[VPT], bool asc) {
    #pragma unroll
    for (int j = VPT / 2; j >= 1; j >>= 1) {
        #pragma unroll
        for (int e = 0; e < VPT; ++e) {
            if ((e & j) == 0) {
                float a = v[e], b = v[e | j];
                float mn = fminf(a, b), mx = fmaxf(a, b);
                v[e]     = asc ? mn : mx;
                v[e | j] = asc ? mx : mn;
            }
        }
    }
}

// (256,4): VGPR cap 64. The epilogue is now histogram-based, so v[32]/c8 die at
// the merge and the true live set is ~50 regs -> no spill expected (R3 spilled
// because bisection kept 40+ regs live). Occupancy model from R1-R7: waves/SIMD
// ~ 256/VGPR; at 64 -> 4/SIMD, LDS 41 KB -> 3 blocks/CU -> ~37%.
__global__ __launch_bounds__(NB, 4) void swd_kernel(
    const float* __restrict__ Xs, const float* __restrict__ Xt,
    const float* __restrict__ Us, float* __restrict__ out)
{
    __shared__ float keys[NMERGE];   // sorted u || sorted v (swizzled); 32 KB
    __shared__ float hist[HBINS];    // delta-weight per clamped cdf level; 8 KB
    __shared__ float wsum[4];        // per-wave partials
    __shared__ int   s_cstar;
    __shared__ int   s_oor;

    const int tid  = threadIdx.x;
    const int arr  = tid >> 7;       // 0 = Xs, 1 = Xt
    const int c    = tid & 127;      // chunk index within array (32 elems/chunk)
    const int lane = tid & 63;
    const int wid  = tid >> 6;       // 0..3
    const int p    = blockIdx.x;

    const float u00 = Us[p*6+0], u01 = Us[p*6+1];
    const float u10 = Us[p*6+2], u11 = Us[p*6+3];
    const float u20 = Us[p*6+4], u21 = Us[p*6+5];

    const float pi_f   = 3.14159265358979323846f;
    const float inv2pi = 0.15915494309189535f;

    const float* __restrict__ X = arr ? Xt : Xs;

    // ---- angles into registers (atan2 is scale-invariant; F.normalize skipped) ----
    float v[VPT];
    {
        const float4* X4 = (const float4*)(X + c * (VPT * 3));  // 96 floats, 16B aligned
        #pragma unroll
        for (int t = 0; t < 8; ++t) {
            float4 q0 = X4[t*3+0], q1 = X4[t*3+1], q2 = X4[t*3+2];
            #define ANG(x,y,z) ((atan2f(-((x)*u01+(y)*u11+(z)*u21), \
                                        -((x)*u00+(y)*u10+(z)*u20)) + pi_f) * inv2pi)
            v[t*4+0] = ANG(q0.x, q0.y, q0.z);
            v[t*4+1] = ANG(q0.w, q1.x, q1.y);
            v[t*4+2] = ANG(q1.z, q1.w, q2.x);
            v[t*4+3] = ANG(q2.y, q2.z, q2.w);
            #undef ANG
            __builtin_amdgcn_sched_barrier(0);
        }
    }

    // init hist & flags (visible after the sort-phase barriers)
    for (int i = tid; i < HBINS; i += NB) hist[i] = 0.0f;
    if (tid == 0) { s_cstar = HBINS - 1; s_oor = 0; }

    // ---- phases k=2..16: intra-thread, compile-time directions ----
    #pragma unroll
    for (int k = 2; k <= 16; k <<= 1) {
        #pragma unroll
        for (int j = k >> 1; j >= 1; j >>= 1) {
            #pragma unroll
            for (int e = 0; e < VPT; ++e) {
                if ((e & j) == 0) {
                    bool asc = ((e & k) == 0);
                    float a = v[e], b = v[e | j];
                    float mn = fminf(a, b), mx = fmaxf(a, b);
                    v[e]     = asc ? mn : mx;
                    v[e | j] = asc ? mx : mn;
                }
            }
        }
    }

    // ---- phase k=32: fully local, direction uniform per thread ----
    local_merge(v, (c & 1) == 0);

    // ---- phases k=64..2048: within-wave shfl_xor exchanges + local merge ----
    #pragma unroll
    for (int k = 64; k <= 2048; k <<= 1) {
        bool asc = ((c & (k >> 5)) == 0);
        #pragma unroll
        for (int d = k >> 6; d >= 1; d >>= 1) {     // j = k/2 .. 32
            bool keepmin = (((c & d) == 0) == asc);
            #pragma unroll
            for (int e = 0; e < VPT; ++e) {
                float o = __shfl_xor(v[e], d, 64);
                v[e] = keepmin ? fminf(v[e], o) : fmaxf(v[e], o);
            }
        }
        local_merge(v, asc);
    }

    // ---- phase k=4096 (full ascending merge) ----
    // j=2048 crosses waves (chunk xor 64): one LDS round-trip.
    #pragma unroll
    for (int e = 0; e < VPT; ++e) keys[sw(tid * VPT + e)] = v[e];
    __syncthreads();
    {
        const int pb = (tid ^ 64) * VPT;
        const bool keepmin = (c & 64) == 0;          // asc = true
        #pragma unroll
        for (int e = 0; e < VPT; ++e) {
            float o = keys[sw(pb + e)];
            v[e] = keepmin ? fminf(v[e], o) : fmaxf(v[e], o);
        }
    }
    __syncthreads();   // all partner reads complete before keys is overwritten
    #pragma unroll
    for (int d = 32; d >= 1; d >>= 1) {              // j = 1024 .. 32
        bool keepmin = ((c & d) == 0);
        #pragma unroll
        for (int e = 0; e < VPT; ++e) {
            float o = __shfl_xor(v[e], d, 64);
            v[e] = keepmin ? fminf(v[e], o) : fmaxf(v[e], o);
        }
    }
    local_merge(v, true);

    // store sorted arrays for the merge; v[] is DEAD after this (reg pressure drop)
    #pragma unroll
    for (int e = 0; e < VPT; ++e) keys[sw(tid * VPT + e)] = v[e];
    __syncthreads();

    // ---- merge-path merge; scatter delta straight into level histogram ----
    // Level after merged element = (#u taken) - (#v taken); cdf value = c/4096 exact.
    int lo0;
    {
        const int d0 = tid * VPT;
        int lo = d0 > NPTS ? d0 - NPTS : 0;
        int hi = d0 < NPTS ? d0 : NPTS;
        while (lo < hi) {                     // ties: u first (stable argsort)
            int mid = (lo + hi) >> 1;
            if (keys[sw(mid)] <= keys[sw(NPTS + (d0 - 1 - mid))]) lo = mid + 1; else hi = mid;
        }
        lo0 = lo;
        int i = lo, j = d0 - lo;
        const float FMAXV = 3.402823466e+38f;
        float cu = (i < NPTS) ? keys[sw(i)] : FMAXV;
        float cv = (j < NPTS) ? keys[sw(NPTS + j)] : FMAXV;
        bool oor = false;
        #pragma unroll
        for (int s = 0; s < VPT; ++s) {
            float cur;
            if (cu <= cv) { cur = cu; ++i; cu = (i < NPTS) ? keys[sw(i)] : FMAXV; }
            else          { cur = cv; ++j; cv = (j < NPTS) ? keys[sw(NPTS + j)] : FMAXV; }
            float nxt = fminf(cu, cv);
            if (nxt == FMAXV) nxt = 1.0f;     // vals_pad appends 1.0
            int b  = (i - j) + HOFF;
            int bc = b < 0 ? 0 : (b > HBINS - 1 ? HBINS - 1 : b);
            oor |= (b != bc);
            atomicAdd(&hist[bc], nxt - cur);
        }
        if (oor) s_oor = 1;                   // never on this data (|c| ~ 130)
    }
    __syncthreads();

    if (s_oor == 0) {
        // ---- level median: parallel prefix over 256 column sums (8 bins each) ----
        const int base = tid * (HBINS / NB);
        float colsum = 0.0f;
        #pragma unroll
        for (int k = 0; k < HBINS / NB; ++k) colsum += hist[base + k];

        float ps = colsum;
        #pragma unroll
        for (int o = 1; o < 64; o <<= 1) {
            float t2 = __shfl_up(ps, o, 64);
            if (lane >= o) ps += t2;
        }
        if (lane == 63) wsum[wid] = ps;
        __syncthreads();
        float wbase = 0.0f;
        #pragma unroll
        for (int w = 0; w < 4; ++w) wbase += (w < wid) ? wsum[w] : 0.0f;
        float incl = wbase + ps;
        float excl = incl - colsum;
        if (incl >= 0.5f && excl < 0.5f + 1e-6f) {
            float run = excl;
            int found = base + (HBINS / NB) - 1;
            #pragma unroll
            for (int k = 0; k < HBINS / NB; ++k) {
                run += hist[base + k];
                if (run >= 0.5f) { found = base + k; break; }
            }
            atomicMin(&s_cstar, found);
        }
        __syncthreads();
        const int cb = s_cstar;               // c* as a bin index

        // ---- w1 = (1/4096) * sum_b hist[b] * |b - cb| ----
        float part = 0.0f;
        #pragma unroll
        for (int k = 0; k < HBINS / NB; ++k) {
            int b = base + k;
            part += hist[b] * fabsf((float)(b - cb));
        }
        #pragma unroll
        for (int o = 32; o >= 1; o >>= 1) part += __shfl_down(part, o, 64);
        if (lane == 0) wsum[wid] = part;      // prior reads of wsum are pre-barrier
        __syncthreads();
        if (tid == 0) {
            float w1 = (wsum[0] + wsum[1] + wsum[2] + wsum[3]) * (1.0f / 4096.0f);
            atomicAdd(out, w1 * (1.0f / (float)NPROJ));
        }
    } else {
        // ---- exact fallback: bisection with merge re-walks (dead on this data) ----
        const int d0 = tid * VPT;
        const float FMAXV = 3.402823466e+38f;
        int lo_c = -4097, hi_c = 4096;
        #pragma unroll 1
        for (int it = 0; it < 14; ++it) {
            const int mid = (lo_c + hi_c) >> 1;
            int i = lo0, j = d0 - lo0;
            float cu = (i < NPTS) ? keys[sw(i)] : FMAXV;
            float cv = (j < NPTS) ? keys[sw(NPTS + j)] : FMAXV;
            float s_loc = 0.0f;
            #pragma unroll 1
            for (int s = 0; s < VPT; ++s) {
                float cur;
                if (cu <= cv) { cur = cu; ++i; cu = (i < NPTS) ? keys[sw(i)] : FMAXV; }
                else          { cur = cv; ++j; cv = (j < NPTS) ? keys[sw(NPTS + j)] : FMAXV; }
                float nxt = fminf(cu, cv);
                if (nxt == FMAXV) nxt = 1.0f;
                if ((i - j) <= mid) s_loc += nxt - cur;
            }
            #pragma unroll
            for (int o = 32; o >= 1; o >>= 1) s_loc += __shfl_down(s_loc, o, 64);
            __syncthreads();
            if (lane == 0) wsum[wid] = s_loc;
            __syncthreads();
            float S = wsum[0] + wsum[1] + wsum[2] + wsum[3];
            if (S >= 0.5f) hi_c = mid; else lo_c = mid;
        }
        const int cs = hi_c;
        int i = lo0, j = d0 - lo0;
        float cu = (i < NPTS) ? keys[sw(i)] : FMAXV;
        float cv = (j < NPTS) ? keys[sw(NPTS + j)] : FMAXV;
        float part = 0.0f;
        #pragma unroll 1
        for (int s = 0; s < VPT; ++s) {
            float cur;
            if (cu <= cv) { cur = cu; ++i; cu = (i < NPTS) ? keys[sw(i)] : FMAXV; }
            else          { cur = cv; ++j; cv = (j < NPTS) ? keys[sw(NPTS + j)] : FMAXV; }
            float nxt = fminf(cu, cv);
            if (nxt == FMAXV) nxt = 1.0f;
            part += (nxt - cur) * fabsf((float)((i - j) - cs));
        }
        #pragma unroll
        for (int o = 32; o >= 1; o >>= 1) part += __shfl_down(part, o, 64);
        __syncthreads();
        if (lane == 0) wsum[wid] = part;
        __syncthreads();
        if (tid == 0) {
            float w1 = (wsum[0] + wsum[1] + wsum[2] + wsum[3]) * (1.0f / 4096.0f);
            atomicAdd(out, w1 * (1.0f / (float)NPROJ));
        }
    }
}

extern "C" void kernel_launch(void* const* d_in, const int* in_sizes, int n_in,
                              void* d_out, int out_size, void* d_ws, size_t ws_size,
                              hipStream_t stream) {
    const float* Xs = (const float*)d_in[0];
    const float* Xt = (const float*)d_in[1];
    const float* Us = (const float*)d_in[2];
    float* out = (float*)d_out;

    hipMemsetAsync(out, 0, sizeof(float), stream);
    swd_kernel<<<NPROJ, NB, 0, stream>>>(Xs, Xt, Us, out);
}